// Round 1
// baseline (446.576 us; speedup 1.0000x reference)
//
#include <hip/hip_runtime.h>

#define DD 32   // node/output dim
#define HH 64   // psi hidden
// PSI_IN = 5*32 = 160

#define XSTR 72   // bf16 stride for xbuf rows (16B-aligned b128 reads)
#define DSTR 33   // f32 stride for hdiff rows (2-way max conflict on writes)

typedef __attribute__((ext_vector_type(8))) short bf16x8;   // 8 bf16 = 4 VGPRs
typedef __attribute__((ext_vector_type(4))) float f32x4;

static __device__ __forceinline__ unsigned short f2bf(float x) {
    // round-to-nearest-even bf16 (inputs are finite; no NaN handling needed)
    union { float f; unsigned u; } v; v.f = x;
    unsigned r = (v.u + 0x7FFFu + ((v.u >> 16) & 1u)) >> 16;
    return (unsigned short)r;
}

// Convert w0/w1/w2 to bf16 MFMA B-fragment order.
// 32 frags total: [0..19] = w0 (kk*4+t), [20..27] = w1 (kk*4+t), [28..31] = w2 (kk*2+t).
// Frag f, lane l (n = t*16 + (l&15), k = kk*32 + (l>>4)*8 + j): 8 bf16 at frags[f*512 + l*8].
__global__ __launch_bounds__(256) void prep_weights(
    const float* __restrict__ w0, const float* __restrict__ w1,
    const float* __restrict__ w2, unsigned short* __restrict__ frags)
{
    const int tid = blockIdx.x * 256 + threadIdx.x;
    const int f = tid >> 6, l = tid & 63;
    if (f >= 32) return;
    const int c = l & 15, q = l >> 4;
    unsigned short* dst = frags + f * 512 + l * 8;
    if (f < 20) {
        const int kk = f >> 2, t = f & 3;
        const int n = t * 16 + c, kb = kk * 32 + q * 8;
        #pragma unroll
        for (int j = 0; j < 8; ++j) dst[j] = f2bf(w0[(kb + j) * HH + n]);
    } else if (f < 28) {
        const int f2 = f - 20, kk = f2 >> 2, t = f2 & 3;
        const int n = t * 16 + c, kb = kk * 32 + q * 8;
        #pragma unroll
        for (int j = 0; j < 8; ++j) dst[j] = f2bf(w1[(kb + j) * HH + n]);
    } else {
        const int f3 = f - 28, kk = f3 >> 1, t = f3 & 1;
        const int n = t * 16 + c, kb = kk * 32 + q * 8;
        #pragma unroll
        for (int j = 0; j < 8; ++j) dst[j] = f2bf(w2[(kb + j) * DD + n]);
    }
}

// One wave per 16-edge tile (grid-stride). 3-layer MLP via mfma_f32_16x16x32_bf16.
// w0/w1 B-frags live in block-shared LDS (28 KB, read per MFMA); w2 in 16 VGPRs.
// This frees ~112 VGPRs/wave vs the all-register version -> 4 waves/SIMD.
// hdiff = (h_dj - h_di) and receiver indices are stashed in per-wave LDS during the
// layer-0 gather, so the epilogue does ZERO redundant global loads.
// Per-wave LDS buffers need no barriers: DS ops from one wave execute in order.
__global__ __launch_bounds__(512, 4) void edge_mfma(
    const float* __restrict__ h_d, const float* __restrict__ h_s,
    const float* __restrict__ ef,
    const int* __restrict__ snd, const int* __restrict__ rcv,
    const unsigned short* __restrict__ frags,
    const float* __restrict__ b0, const float* __restrict__ b1,
    const float* __restrict__ b2,
    float* __restrict__ agg, int E, int ntiles)
{
    __shared__ __align__(16) unsigned short wlds[28 * 512];      // 28 KB: w0+w1 frags
    __shared__ __align__(16) unsigned short xbuf[8][16 * XSTR];  // 18 KB: x1/x2 (reused)
    __shared__ float hdiff[8][16 * DSTR];                        // 16.5 KB
    __shared__ int rcvb[8][16];                                  // 0.5 KB  => 64512 B total

    const int lane = threadIdx.x & 63;
    const int w = threadIdx.x >> 6;          // wave in block, 0..7
    const int c = lane & 15, q = lane >> 4;

    // stage w0/w1 fragments to LDS (28 KB, 16B chunks, coalesced)
    for (int i = threadIdx.x; i < 28 * 512 / 8; i += 512)
        ((float4*)wlds)[i] = ((const float4*)frags)[i];
    // w2 fragments stay in registers (16 VGPRs)
    bf16x8 wf2[4];
    #pragma unroll
    for (int t = 0; t < 4; ++t)
        wf2[t] = *(const bf16x8*)(frags + (28 + t) * 512 + lane * 8);
    __syncthreads();

    const float b0t[4] = {b0[c], b0[16 + c], b0[32 + c], b0[48 + c]};
    const float b1t[4] = {b1[c], b1[16 + c], b1[32 + c], b1[48 + c]};
    const float b2t[2] = {b2[c], b2[16 + c]};

    unsigned short* xb = xbuf[w];
    float* hd = hdiff[w];
    int* rb = rcvb[w];

    const int wave_id = blockIdx.x * 8 + w;
    const int nwaves = gridDim.x * 8;

    // prefetch first tile's indices (m = c = lane&15 is the edge row)
    int nsi = 0, nri = 0;
    if (wave_id < ntiles) {
        int e0 = wave_id * 16 + c; if (e0 >= E) e0 = E - 1;
        nsi = snd[e0]; nri = rcv[e0];
    }

    for (int tile = wave_id; tile < ntiles; tile += nwaves) {
        const int base = tile * 16;
        const int si = nsi, ri = nri;
        {   // prefetch NEXT tile's indices: load latency hides under this tile's MLP
            const int nt = tile + nwaves;
            if (nt < ntiles) {
                int e2 = nt * 16 + c; if (e2 >= E) e2 = E - 1;
                nsi = snd[e2]; nri = rcv[e2];
            }
        }
        int e = base + c; if (e >= E) e = E - 1;

        // ---- gather the 5 source rows (lane covers cols q*8.. of edge row c) ----
        const float* ps = h_s + (size_t)si * DD + q * 8;
        const float* pr = h_s + (size_t)ri * DD + q * 8;
        const float* qs = h_d + (size_t)si * DD + q * 8;
        const float* qr = h_d + (size_t)ri * DD + q * 8;
        const float* pe = ef  + (size_t)e  * DD + q * 8;
        float4 g[10];
        g[0] = ((const float4*)ps)[0]; g[1] = ((const float4*)ps)[1];
        g[2] = ((const float4*)pr)[0]; g[3] = ((const float4*)pr)[1];
        g[4] = ((const float4*)qs)[0]; g[5] = ((const float4*)qs)[1];
        g[6] = ((const float4*)qr)[0]; g[7] = ((const float4*)qr)[1];
        g[8] = ((const float4*)pe)[0]; g[9] = ((const float4*)pe)[1];

        // stash h_dj - h_di (row c, cols q*8..q*8+7) + receiver for the epilogue
        hd[c * DSTR + q * 8 + 0] = g[6].x - g[4].x;
        hd[c * DSTR + q * 8 + 1] = g[6].y - g[4].y;
        hd[c * DSTR + q * 8 + 2] = g[6].z - g[4].z;
        hd[c * DSTR + q * 8 + 3] = g[6].w - g[4].w;
        hd[c * DSTR + q * 8 + 4] = g[7].x - g[5].x;
        hd[c * DSTR + q * 8 + 5] = g[7].y - g[5].y;
        hd[c * DSTR + q * 8 + 6] = g[7].z - g[5].z;
        hd[c * DSTR + q * 8 + 7] = g[7].w - g[5].w;
        if (q == 0) rb[c] = ri;

        // ---- layer 0: [16x160] @ [160x64], A-frags direct from gathers ----
        f32x4 c0[4] = {f32x4{0,0,0,0}, f32x4{0,0,0,0}, f32x4{0,0,0,0}, f32x4{0,0,0,0}};
        #pragma unroll
        for (int kk = 0; kk < 5; ++kk) {
            const float4 v0 = g[2 * kk], v1 = g[2 * kk + 1];
            bf16x8 a;
            a[0] = (short)f2bf(v0.x); a[1] = (short)f2bf(v0.y);
            a[2] = (short)f2bf(v0.z); a[3] = (short)f2bf(v0.w);
            a[4] = (short)f2bf(v1.x); a[5] = (short)f2bf(v1.y);
            a[6] = (short)f2bf(v1.z); a[7] = (short)f2bf(v1.w);
            #pragma unroll
            for (int t = 0; t < 4; ++t) {
                const bf16x8 b = *(const bf16x8*)(wlds + (kk * 4 + t) * 512 + lane * 8);
                c0[t] = __builtin_amdgcn_mfma_f32_16x16x32_bf16(a, b, c0[t], 0, 0, 0);
            }
        }
        // relu(C + b0) -> X1 (row = q*4+r = edge, col = t*16+c)
        #pragma unroll
        for (int t = 0; t < 4; ++t) {
            #pragma unroll
            for (int r = 0; r < 4; ++r) {
                const float v = fmaxf(c0[t][r] + b0t[t], 0.0f);
                xb[(q * 4 + r) * XSTR + t * 16 + c] = f2bf(v);
            }
        }

        // ---- layer 1: [16x64] @ [64x64] (reads all of x1 before overwriting) ----
        f32x4 c1[4] = {f32x4{0,0,0,0}, f32x4{0,0,0,0}, f32x4{0,0,0,0}, f32x4{0,0,0,0}};
        #pragma unroll
        for (int kk = 0; kk < 2; ++kk) {
            const bf16x8 a = *(const bf16x8*)(xb + c * XSTR + kk * 32 + q * 8);
            #pragma unroll
            for (int t = 0; t < 4; ++t) {
                const bf16x8 b = *(const bf16x8*)(wlds + (20 + kk * 4 + t) * 512 + lane * 8);
                c1[t] = __builtin_amdgcn_mfma_f32_16x16x32_bf16(a, b, c1[t], 0, 0, 0);
            }
        }
        #pragma unroll
        for (int t = 0; t < 4; ++t) {
            #pragma unroll
            for (int r = 0; r < 4; ++r) {
                const float v = fmaxf(c1[t][r] + b1t[t], 0.0f);
                xb[(q * 4 + r) * XSTR + t * 16 + c] = f2bf(v);
            }
        }

        // ---- layer 2: [16x64] @ [64x32], B from registers ----
        f32x4 c2[2] = {f32x4{0,0,0,0}, f32x4{0,0,0,0}};
        #pragma unroll
        for (int kk = 0; kk < 2; ++kk) {
            const bf16x8 a = *(const bf16x8*)(xb + c * XSTR + kk * 32 + q * 8);
            #pragma unroll
            for (int t = 0; t < 2; ++t)
                c2[t] = __builtin_amdgcn_mfma_f32_16x16x32_bf16(a, wf2[kk * 2 + t], c2[t], 0, 0, 0);
        }

        // ---- epilogue: s_ij = relu(psi)*(h_dj - h_di) from LDS, scatter-add ----
        int rir[4];
        #pragma unroll
        for (int r = 0; r < 4; ++r) rir[r] = rb[q * 4 + r];
        #pragma unroll
        for (int t = 0; t < 2; ++t) {
            const int h = t * 16 + c;               // C/D col = output dim
            #pragma unroll
            for (int r = 0; r < 4; ++r) {
                const int ee = base + q * 4 + r;    // C/D row = edge index
                if (ee < E) {
                    const float psi = fmaxf(c2[t][r] + b2t[t], 0.0f);
                    const float d = hd[(q * 4 + r) * DSTR + h];
                    atomicAdd(agg + (size_t)rir[r] * DD + h, psi * d);
                }
            }
        }
    }
}

// out[n][d] = h_d_prev[n][d] + sum_k agg[n][k] * W[k][d]
__global__ __launch_bounds__(256) void out_kernel(
    const float* __restrict__ h_d, const float* __restrict__ agg,
    const float* __restrict__ W, float* __restrict__ out, int N)
{
    const int idx = blockIdx.x * 256 + threadIdx.x;
    if (idx >= N * DD) return;
    const int n = idx >> 5;
    const int d = idx & 31;
    const float* arow = agg + (size_t)n * DD;
    float s = h_d[idx];
    #pragma unroll
    for (int k = 0; k < DD; ++k) s = fmaf(arow[k], W[k * DD + d], s);
    out[idx] = s;
}

extern "C" void kernel_launch(void* const* d_in, const int* in_sizes, int n_in,
                              void* d_out, int out_size, void* d_ws, size_t ws_size,
                              hipStream_t stream) {
    const float* h_d = (const float*)d_in[0];
    const float* h_s = (const float*)d_in[1];
    const float* ef  = (const float*)d_in[2];
    const int*   snd = (const int*)d_in[3];
    const int*   rcv = (const int*)d_in[4];
    const float* w0  = (const float*)d_in[5];
    const float* b0  = (const float*)d_in[6];
    const float* w1  = (const float*)d_in[7];
    const float* b1  = (const float*)d_in[8];
    const float* w2  = (const float*)d_in[9];
    const float* b2  = (const float*)d_in[10];
    const float* W   = (const float*)d_in[11];
    float* out = (float*)d_out;

    const int N = in_sizes[0] / DD;
    const int E = in_sizes[3];
    const int ntiles = (E + 15) / 16;

    // d_ws layout: [0, N*DD floats) = agg ; then 32 KB of bf16 weight frags
    float* agg = (float*)d_ws;
    unsigned short* frags = (unsigned short*)((char*)d_ws + (size_t)N * DD * sizeof(float));

    hipMemsetAsync(agg, 0, (size_t)N * DD * sizeof(float), stream);
    prep_weights<<<8, 256, 0, stream>>>(w0, w1, w2, frags);
    edge_mfma<<<512, 512, 0, stream>>>(h_d, h_s, ef, snd, rcv, frags,
                                       b0, b1, b2, agg, E, ntiles);
    out_kernel<<<((N * DD) + 255) / 256, 256, 0, stream>>>(h_d, agg, W, out, N);
}

// Round 2
// 410.232 us; speedup vs baseline: 1.0886x; 1.0886x over previous
//
#include <hip/hip_runtime.h>

#define DD 32   // node/output dim
#define HH 64   // psi hidden
// PSI_IN = 5*32 = 160

#define XSTR 72   // bf16 stride for xbuf rows (16B-aligned b128 reads)
#define DSTR 35   // f32 stride for hdiff rows (<=2-way bank conflicts both phases)

typedef __attribute__((ext_vector_type(8))) short bf16x8;   // 8 bf16 = 4 VGPRs
typedef __attribute__((ext_vector_type(4))) float f32x4;

static __device__ __forceinline__ unsigned short f2bf(float x) {
    // round-to-nearest-even bf16 (inputs are finite; no NaN handling needed)
    union { float f; unsigned u; } v; v.f = x;
    unsigned r = (v.u + 0x7FFFu + ((v.u >> 16) & 1u)) >> 16;
    return (unsigned short)r;
}

static __device__ __forceinline__ float bf2f(unsigned short x) {
    union { unsigned u; float f; } v; v.u = ((unsigned)x) << 16;
    return v.f;
}

// Convert w0/w1/w2 to bf16 MFMA B-fragment order.
// 32 frags total: [0..19] = w0 (kk*4+t), [20..27] = w1 (kk*4+t), [28..31] = w2 (kk*2+t).
// Frag f, lane l (n = t*16 + (l&15), k = kk*32 + (l>>4)*8 + j): 8 bf16 at frags[f*512 + l*8].
__global__ __launch_bounds__(256) void prep_weights(
    const float* __restrict__ w0, const float* __restrict__ w1,
    const float* __restrict__ w2, unsigned short* __restrict__ frags)
{
    const int tid = blockIdx.x * 256 + threadIdx.x;
    const int f = tid >> 6, l = tid & 63;
    if (f >= 32) return;
    const int c = l & 15, q = l >> 4;
    unsigned short* dst = frags + f * 512 + l * 8;
    if (f < 20) {
        const int kk = f >> 2, t = f & 3;
        const int n = t * 16 + c, kb = kk * 32 + q * 8;
        #pragma unroll
        for (int j = 0; j < 8; ++j) dst[j] = f2bf(w0[(kb + j) * HH + n]);
    } else if (f < 28) {
        const int f2 = f - 20, kk = f2 >> 2, t = f2 & 3;
        const int n = t * 16 + c, kb = kk * 32 + q * 8;
        #pragma unroll
        for (int j = 0; j < 8; ++j) dst[j] = f2bf(w1[(kb + j) * HH + n]);
    } else {
        const int f3 = f - 28, kk = f3 >> 1, t = f3 & 1;
        const int n = t * 16 + c, kb = kk * 32 + q * 8;
        #pragma unroll
        for (int j = 0; j < 8; ++j) dst[j] = f2bf(w2[(kb + j) * DD + n]);
    }
}

// Pack per-node features into ONE 128B bf16 row: npack[n] = [h_s[n][0..31] | h_d[n][0..31]].
// Gathers in edge_mfma then touch 2 cache lines/edge instead of 4, and the
// gather working set halves (25.6 MB fp32 -> 12.8 MB bf16).
__global__ __launch_bounds__(256) void pack_nodes(
    const float* __restrict__ h_d, const float* __restrict__ h_s,
    unsigned short* __restrict__ npack, int N)
{
    const int tid = blockIdx.x * 256 + threadIdx.x;   // one thread per 8 elems
    if (tid >= N * 8) return;
    const int n = tid >> 3, chunk = tid & 7;
    const float* src = (chunk < 4) ? (h_s + (size_t)n * DD + chunk * 8)
                                   : (h_d + (size_t)n * DD + (chunk - 4) * 8);
    const float4 v0 = ((const float4*)src)[0];
    const float4 v1 = ((const float4*)src)[1];
    unsigned short* dst = npack + (size_t)n * 64 + chunk * 8;
    dst[0] = f2bf(v0.x); dst[1] = f2bf(v0.y); dst[2] = f2bf(v0.z); dst[3] = f2bf(v0.w);
    dst[4] = f2bf(v1.x); dst[5] = f2bf(v1.y); dst[6] = f2bf(v1.z); dst[7] = f2bf(v1.w);
}

// One wave per 16-edge tile (grid-stride). 3-layer MLP via mfma_f32_16x16x32_bf16.
// Node gathers come from the packed bf16 array (2 lines/edge). ef + indices are
// streamed with non-temporal loads so they don't evict node rows / agg lines from
// the 4MB-per-XCD L2. w0 B-frags in block LDS (20KB); w1/w2 in registers (48 VGPRs)
// -- fits the 128-reg budget for 4 waves/SIMD. hdiff + receiver idx stashed in
// per-wave LDS so the epilogue does zero global loads.
__global__ __launch_bounds__(512, 4) void edge_mfma(
    const unsigned short* __restrict__ npack,
    const float* __restrict__ ef,
    const int* __restrict__ snd, const int* __restrict__ rcv,
    const unsigned short* __restrict__ frags,
    const float* __restrict__ b0, const float* __restrict__ b1,
    const float* __restrict__ b2,
    float* __restrict__ agg, int E, int ntiles)
{
    __shared__ __align__(16) unsigned short wlds[20 * 512];      // 20 KB: w0 frags
    __shared__ __align__(16) unsigned short xbuf[8][16 * XSTR];  // 18 KB: x1/x2 (reused)
    __shared__ float hdiff[8][16 * DSTR];                        // 17.5 KB
    __shared__ int rcvb[8][16];                                  // 0.5 KB => 57 KB total

    const int lane = threadIdx.x & 63;
    const int w = threadIdx.x >> 6;          // wave in block, 0..7
    const int c = lane & 15, q = lane >> 4;

    // stage w0 fragments to LDS (20 KB, 16B chunks, coalesced)
    for (int i = threadIdx.x; i < 20 * 512 / 8; i += 512)
        ((float4*)wlds)[i] = ((const float4*)frags)[i];
    // w1 (8 frags) + w2 (4 frags) stay in registers
    bf16x8 wf1[8], wf2[4];
    #pragma unroll
    for (int t = 0; t < 8; ++t)
        wf1[t] = *(const bf16x8*)(frags + (20 + t) * 512 + lane * 8);
    #pragma unroll
    for (int t = 0; t < 4; ++t)
        wf2[t] = *(const bf16x8*)(frags + (28 + t) * 512 + lane * 8);
    __syncthreads();

    const float b0t[4] = {b0[c], b0[16 + c], b0[32 + c], b0[48 + c]};
    const float b1t[4] = {b1[c], b1[16 + c], b1[32 + c], b1[48 + c]};
    const float b2t[2] = {b2[c], b2[16 + c]};

    unsigned short* xb = xbuf[w];
    float* hd = hdiff[w];
    int* rb = rcvb[w];

    const int wave_id = blockIdx.x * 8 + w;
    const int nwaves = gridDim.x * 8;

    // prefetch first tile's indices (m = c = lane&15 is the edge row)
    int nsi = 0, nri = 0;
    if (wave_id < ntiles) {
        int e0 = wave_id * 16 + c; if (e0 >= E) e0 = E - 1;
        nsi = __builtin_nontemporal_load(snd + e0);
        nri = __builtin_nontemporal_load(rcv + e0);
    }

    for (int tile = wave_id; tile < ntiles; tile += nwaves) {
        const int base = tile * 16;
        const int si = nsi, ri = nri;
        {   // prefetch NEXT tile's indices: load latency hides under this tile's MLP
            const int nt = tile + nwaves;
            if (nt < ntiles) {
                int e2 = nt * 16 + c; if (e2 >= E) e2 = E - 1;
                nsi = __builtin_nontemporal_load(snd + e2);
                nri = __builtin_nontemporal_load(rcv + e2);
            }
        }
        int e = base + c; if (e >= E) e = E - 1;

        // ---- gather: 2 packed node rows + streaming ef (lane covers cols q*8..) ----
        const unsigned short* nps = npack + (size_t)si * 64 + q * 8;
        const unsigned short* npr = npack + (size_t)ri * 64 + q * 8;
        const bf16x8 a_ss = *(const bf16x8*)nps;          // h_s[sender]
        const bf16x8 a_sr = *(const bf16x8*)npr;          // h_s[receiver]
        const bf16x8 a_ds = *(const bf16x8*)(nps + 32);   // h_d[sender]
        const bf16x8 a_dr = *(const bf16x8*)(npr + 32);   // h_d[receiver]
        const f32x4 e0v = __builtin_nontemporal_load((const f32x4*)(ef + (size_t)e * DD + q * 8));
        const f32x4 e1v = __builtin_nontemporal_load((const f32x4*)(ef + (size_t)e * DD + q * 8) + 1);

        // stash h_dj - h_di (row c, cols q*8..q*8+7) + receiver for the epilogue
        #pragma unroll
        for (int j = 0; j < 8; ++j)
            hd[c * DSTR + q * 8 + j] =
                bf2f((unsigned short)a_dr[j]) - bf2f((unsigned short)a_ds[j]);
        if (q == 0) rb[c] = ri;

        bf16x8 aef;
        aef[0] = (short)f2bf(e0v[0]); aef[1] = (short)f2bf(e0v[1]);
        aef[2] = (short)f2bf(e0v[2]); aef[3] = (short)f2bf(e0v[3]);
        aef[4] = (short)f2bf(e1v[0]); aef[5] = (short)f2bf(e1v[1]);
        aef[6] = (short)f2bf(e1v[2]); aef[7] = (short)f2bf(e1v[3]);

        // ---- layer 0: [16x160] @ [160x64], A-frags direct from gathers ----
        const bf16x8 af[5] = {a_ss, a_sr, a_ds, a_dr, aef};
        f32x4 c0[4] = {f32x4{0,0,0,0}, f32x4{0,0,0,0}, f32x4{0,0,0,0}, f32x4{0,0,0,0}};
        #pragma unroll
        for (int kk = 0; kk < 5; ++kk) {
            #pragma unroll
            for (int t = 0; t < 4; ++t) {
                const bf16x8 b = *(const bf16x8*)(wlds + (kk * 4 + t) * 512 + lane * 8);
                c0[t] = __builtin_amdgcn_mfma_f32_16x16x32_bf16(af[kk], b, c0[t], 0, 0, 0);
            }
        }
        // relu(C + b0) -> X1 (row = q*4+r = edge, col = t*16+c)
        #pragma unroll
        for (int t = 0; t < 4; ++t) {
            #pragma unroll
            for (int r = 0; r < 4; ++r) {
                const float v = fmaxf(c0[t][r] + b0t[t], 0.0f);
                xb[(q * 4 + r) * XSTR + t * 16 + c] = f2bf(v);
            }
        }

        // ---- layer 1: [16x64] @ [64x64], B from registers ----
        f32x4 c1[4] = {f32x4{0,0,0,0}, f32x4{0,0,0,0}, f32x4{0,0,0,0}, f32x4{0,0,0,0}};
        #pragma unroll
        for (int kk = 0; kk < 2; ++kk) {
            const bf16x8 a = *(const bf16x8*)(xb + c * XSTR + kk * 32 + q * 8);
            #pragma unroll
            for (int t = 0; t < 4; ++t)
                c1[t] = __builtin_amdgcn_mfma_f32_16x16x32_bf16(a, wf1[kk * 4 + t], c1[t], 0, 0, 0);
        }
        #pragma unroll
        for (int t = 0; t < 4; ++t) {
            #pragma unroll
            for (int r = 0; r < 4; ++r) {
                const float v = fmaxf(c1[t][r] + b1t[t], 0.0f);
                xb[(q * 4 + r) * XSTR + t * 16 + c] = f2bf(v);
            }
        }

        // ---- layer 2: [16x64] @ [64x32], B from registers ----
        f32x4 c2[2] = {f32x4{0,0,0,0}, f32x4{0,0,0,0}};
        #pragma unroll
        for (int kk = 0; kk < 2; ++kk) {
            const bf16x8 a = *(const bf16x8*)(xb + c * XSTR + kk * 32 + q * 8);
            #pragma unroll
            for (int t = 0; t < 2; ++t)
                c2[t] = __builtin_amdgcn_mfma_f32_16x16x32_bf16(a, wf2[kk * 2 + t], c2[t], 0, 0, 0);
        }

        // ---- epilogue: s_ij = relu(psi)*(h_dj - h_di) from LDS, scatter-add ----
        int rir[4];
        #pragma unroll
        for (int r = 0; r < 4; ++r) rir[r] = rb[q * 4 + r];
        #pragma unroll
        for (int t = 0; t < 2; ++t) {
            const int h = t * 16 + c;               // C/D col = output dim
            #pragma unroll
            for (int r = 0; r < 4; ++r) {
                const int ee = base + q * 4 + r;    // C/D row = edge index
                if (ee < E) {
                    const float psi = fmaxf(c2[t][r] + b2t[t], 0.0f);
                    const float d = hd[(q * 4 + r) * DSTR + h];
                    atomicAdd(agg + (size_t)rir[r] * DD + h, psi * d);
                }
            }
        }
    }
}

// out[n][d] = h_d_prev[n][d] + sum_k agg[n][k] * W[k][d]
__global__ __launch_bounds__(256) void out_kernel(
    const float* __restrict__ h_d, const float* __restrict__ agg,
    const float* __restrict__ W, float* __restrict__ out, int N)
{
    const int idx = blockIdx.x * 256 + threadIdx.x;
    if (idx >= N * DD) return;
    const int n = idx >> 5;
    const int d = idx & 31;
    const float* arow = agg + (size_t)n * DD;
    float s = h_d[idx];
    #pragma unroll
    for (int k = 0; k < DD; ++k) s = fmaf(arow[k], W[k * DD + d], s);
    out[idx] = s;
}

extern "C" void kernel_launch(void* const* d_in, const int* in_sizes, int n_in,
                              void* d_out, int out_size, void* d_ws, size_t ws_size,
                              hipStream_t stream) {
    const float* h_d = (const float*)d_in[0];
    const float* h_s = (const float*)d_in[1];
    const float* ef  = (const float*)d_in[2];
    const int*   snd = (const int*)d_in[3];
    const int*   rcv = (const int*)d_in[4];
    const float* w0  = (const float*)d_in[5];
    const float* b0  = (const float*)d_in[6];
    const float* w1  = (const float*)d_in[7];
    const float* b1  = (const float*)d_in[8];
    const float* w2  = (const float*)d_in[9];
    const float* b2  = (const float*)d_in[10];
    const float* W   = (const float*)d_in[11];
    float* out = (float*)d_out;

    const int N = in_sizes[0] / DD;
    const int E = in_sizes[3];
    const int ntiles = (E + 15) / 16;

    // d_ws layout: agg (N*DD f32) | frags (32 KB bf16) | npack (N*64 bf16)
    float* agg = (float*)d_ws;
    unsigned short* frags = (unsigned short*)((char*)d_ws + (size_t)N * DD * sizeof(float));
    unsigned short* npack = frags + 32 * 512;

    hipMemsetAsync(agg, 0, (size_t)N * DD * sizeof(float), stream);
    prep_weights<<<8, 256, 0, stream>>>(w0, w1, w2, frags);
    pack_nodes<<<(N * 8 + 255) / 256, 256, 0, stream>>>(h_d, h_s, npack, N);
    edge_mfma<<<512, 512, 0, stream>>>(npack, ef, snd, rcv, frags,
                                       b0, b1, b2, agg, E, ntiles);
    out_kernel<<<((N * DD) + 255) / 256, 256, 0, stream>>>(h_d, agg, W, out, N);
}